// Round 8
// baseline (1137.997 us; speedup 1.0000x reference)
//
#include <hip/hip_runtime.h>
#include <hip/hip_bf16.h>
#include <stdint.h>

typedef __bf16 bf16_t;
typedef bf16_t bf16x8 __attribute__((ext_vector_type(8)));
typedef float  f32x4  __attribute__((ext_vector_type(4)));
typedef int    i32x4  __attribute__((ext_vector_type(4)));

#define M_TOK 2048
#define N_OUT 11008
#define K_IN  4096

#define GLDS16(gptr, lptr)                                                     \
    __builtin_amdgcn_global_load_lds(                                          \
        (__attribute__((address_space(1))) void*)(gptr),                       \
        (__attribute__((address_space(3))) void*)(lptr), 16, 0, 0)

#define VM(N) asm volatile("s_waitcnt vmcnt(" #N ")" ::: "memory")
#define NOP ((void)0)

// ---------------- pre-pass 1: pack W int32 -> i8 (q-128), exact ----------------
__global__ __launch_bounds__(256)
void pack_w(const int* __restrict__ Q, signed char* __restrict__ W8)
{
    const size_t total16 = (size_t)N_OUT * K_IN / 16;
    const size_t stride  = (size_t)gridDim.x * blockDim.x;
    for (size_t i = (size_t)blockIdx.x * blockDim.x + threadIdx.x; i < total16; i += stride) {
        const size_t e0 = i * 16;
        const int4* q4 = (const int4*)(Q + e0);
        unsigned int pk[4];
        #pragma unroll
        for (int j = 0; j < 4; ++j) {
            const int4 q = q4[j];
            pk[j] =  (unsigned int)((q.x - 128) & 255)
                  | ((unsigned int)((q.y - 128) & 255) << 8)
                  | ((unsigned int)((q.z - 128) & 255) << 16)
                  | ((unsigned int)((q.w - 128) & 255) << 24);
        }
        *(int4*)(W8 + e0) = *(const int4*)pk;
    }
}

// ---------------- pre-pass 2: per-token symmetric i8 quant of X ----------------
__global__ __launch_bounds__(256)
void quant_x(const float* __restrict__ X, signed char* __restrict__ X8,
             float* __restrict__ dxv, float* __restrict__ sxv)
{
    const int row = blockIdx.x;
    const int tid = threadIdx.x;
    const float* xr = X + (size_t)row * K_IN + tid * 16;
    float v[16];
    #pragma unroll
    for (int j = 0; j < 4; ++j)
        *(float4*)(v + j * 4) = ((const float4*)xr)[j];

    float amax = 0.f;
    #pragma unroll
    for (int j = 0; j < 16; ++j) amax = fmaxf(amax, fabsf(v[j]));
    #pragma unroll
    for (int m = 1; m < 64; m <<= 1)
        amax = fmaxf(amax, __shfl_xor(amax, m));
    __shared__ float wmax[4];
    __shared__ int   wsum[4];
    const int wv = tid >> 6;
    if ((tid & 63) == 0) wmax[wv] = amax;
    __syncthreads();
    amax = fmaxf(fmaxf(wmax[0], wmax[1]), fmaxf(wmax[2], wmax[3]));
    amax = fmaxf(amax, 1e-20f);
    const float inv = 127.f / amax;

    int sum = 0;
    unsigned int pk[4];
    #pragma unroll
    for (int j = 0; j < 4; ++j) {
        unsigned int p = 0;
        #pragma unroll
        for (int i = 0; i < 4; ++i) {
            int xi = (int)__builtin_rintf(v[j * 4 + i] * inv);
            xi = max(-127, min(127, xi));
            sum += xi;
            p |= ((unsigned int)(xi & 255)) << (8 * i);
        }
        pk[j] = p;
    }
    *(int4*)(X8 + (size_t)row * K_IN + tid * 16) = *(const int4*)pk;

    #pragma unroll
    for (int m = 1; m < 64; m <<= 1) sum += __shfl_xor(sum, m);
    if ((tid & 63) == 0) wsum[wv] = sum;
    __syncthreads();
    if (tid == 0) {
        dxv[row] = amax * (1.f / 127.f);
        sxv[row] = (float)(wsum[0] + wsum[1] + wsum[2] + wsum[3]);
    }
}

// ---------------- main GEMM: i8 128x256, BK=64, 2-buf, 3 blocks/CU -----------
// LDS = 48 KB -> 3 blocks/CU co-resident (all 688 blocks resident at launch,
// no dispatch tail; 24 waves/CU). 3 independent barrier-groups per CU
// interleave their LDS-read bursts with other blocks' MFMA bursts (m114).
// Region t (between barriers t-1 and t):
//   STAGE3(tile t+1) -> buf (t+1)&1   (not read in region t; read at t+1)
//   frag-read tile t <- buf t&1       (staged region t-1, drained there)
//   MFMA tile t
//   VM(0)  (drains OWN tile-(t+1) loads; issued ~full region earlier)
//   s_barrier                          (=> after barrier, ALL waves' loads landed)
// Invariant (round-6 lesson): vmcnt is per-wave -> drain own loads BEFORE the
// barrier, read the staged buffer only AFTER it.

#define ISSUE_A(SB, KT)  GLDS16(gA  + (KT) * 64, (char*)&sA[SB][0][0] + (tid << 4))
#define ISSUE_B0(SB, KT) GLDS16(gB0 + (KT) * 64, (char*)&sB[SB][0][0] + (tid << 4))
#define ISSUE_B1(SB, KT) GLDS16(gB1 + (KT) * 64, (char*)&sB[SB][0][0] + 8192 + (tid << 4))
#define STAGE3(SB, KT) do { ISSUE_A(SB, KT); ISSUE_B0(SB, KT); ISSUE_B1(SB, KT); } while (0)

#define REGION_BODY(BUFN, ISSUE, WAITOP, ENDBAR) do {                          \
    ISSUE;                                                                     \
    i32x4 fa[4], fb[4];                                                        \
    const char* Ab_ = (const char*)&sA[BUFN][0][0];                            \
    const char* Bb_ = (const char*)&sB[BUFN][0][0];                            \
    _Pragma("unroll")                                                          \
    for (int mq = 0; mq < 4; ++mq)                                             \
        fa[mq] = *(const i32x4*)(Ab_ + rowAoff + mq * 1024 + ckA);             \
    _Pragma("unroll")                                                          \
    for (int nq = 0; nq < 4; ++nq)                                             \
        fb[nq] = *(const i32x4*)(Bb_ + rowBoff + nq * 1024 + ckA);             \
    __builtin_amdgcn_s_setprio(1);                                             \
    _Pragma("unroll")                                                          \
    for (int mq = 0; mq < 4; ++mq)                                             \
        _Pragma("unroll")                                                      \
        for (int nq = 0; nq < 4; ++nq)                                         \
            acc[mq][nq] = __builtin_amdgcn_mfma_i32_16x16x64_i8(               \
                fa[mq], fb[nq], acc[mq][nq], 0, 0, 0);                         \
    __builtin_amdgcn_s_setprio(0);                                             \
    WAITOP;                                                                    \
    if (ENDBAR) {                                                              \
        asm volatile("" ::: "memory");                                         \
        __builtin_amdgcn_s_barrier();                                          \
        asm volatile("" ::: "memory");                                         \
    }                                                                          \
} while (0)

#define REGION_S(BUFN, STB, KT2) REGION_BODY(BUFN, STAGE3(STB, KT2), VM(0), 1)
#define REGION_END(BUFN)         REGION_BODY(BUFN, NOP, NOP, 0)

__global__ __launch_bounds__(512, 6)
void gemm_i8(const signed char* __restrict__ A8,   // [M_TOK][K_IN] i8
             const signed char* __restrict__ B8,   // [N_OUT][K_IN] i8
             const float* __restrict__ dxv,        // [M_TOK]
             const float* __restrict__ sxv,        // [M_TOK]
             const float* __restrict__ S,
             const float* __restrict__ Z,
             const float* __restrict__ Bias,
             float* __restrict__ O)
{
    __shared__ signed char sA[2][128][64];   // 16 KB
    __shared__ signed char sB[2][256][64];   // 32 KB  -> 48 KB, 3 blocks/CU

    const int tid  = threadIdx.x;
    const int lane = tid & 63;
    const int wid  = tid >> 6;
    const int wr   = wid >> 2;   // 0..1  (M half)
    const int wc   = wid & 3;    // 0..3  (N quarter)
    const int fr   = lane & 15;
    const int fg   = lane >> 4;

    // XCD swizzle: 688 = 8 * 86
    const int bid = blockIdx.x;
    const int swz = (bid & 7) * 86 + (bid >> 3);
    const int by  = swz / 43;
    const int bx  = swz - by * 43;
    const long bm = (long)by * 128;
    const long bn = (long)bx * 256;

    // staging: thread tid -> LDS chunk tid (row tid>>2, chunk tid&3); source
    // holds global chunk (tid&3) ^ ((row>>1)&3). Rows +128 keep same XOR.
    const int srow = tid >> 2;
    const int scg  = ((tid & 3) ^ ((srow >> 1) & 3)) << 4;
    const signed char* gA  = A8 + (size_t)(bm + srow) * K_IN + scg;
    const signed char* gB0 = B8 + (size_t)(bn + srow) * K_IN + scg;
    const signed char* gB1 = B8 + (size_t)(bn + 128 + srow) * K_IN + scg;

    // ds_read: logical (row, k-chunk fg) at byte row*64 + ((fg^((row>>1)&3))<<4)
    const int ckA     = (fg ^ ((fr >> 1) & 3)) << 4;
    const int rowAoff = (wr * 64 + fr) * 64;
    const int rowBoff = (wc * 64 + fr) * 64;

    i32x4 acc[4][4] = {};

    // prologue: stage tile 0 -> buf 0; drain own loads; barrier.
    STAGE3(0, 0);
    VM(0);
    asm volatile("" ::: "memory");
    __builtin_amdgcn_s_barrier();
    asm volatile("" ::: "memory");

    // regions t = 0..61 (stage tiles 1..62)
    #pragma unroll 1
    for (int i = 0; i < 31; ++i) {
        REGION_S(0, 1, 2 * i + 1);   // t = 2i   : read buf0, stage tile 2i+1 -> buf1
        REGION_S(1, 0, 2 * i + 2);   // t = 2i+1 : read buf1, stage tile 2i+2 -> buf0
    }
    REGION_S(0, 1, 63);              // t = 62: read buf0, stage tile 63 -> buf1
    REGION_END(1);                   // t = 63: read buf1, MFMA only

    // epilogue: y = s*dx*(acc + (128-zp)*sx) + bias
    // C/D: col = lane&15, row = (lane>>4)*4 + reg (shape-determined, verified)
    float dxa[16], sxa[16];
    #pragma unroll
    for (int m = 0; m < 4; ++m)
        #pragma unroll
        for (int r = 0; r < 4; ++r) {
            const int row = (int)bm + wr * 64 + m * 16 + (fg << 2) + r;
            dxa[m * 4 + r] = dxv[row];
            sxa[m * 4 + r] = sxv[row];
        }
    #pragma unroll
    for (int n = 0; n < 4; ++n) {
        const long col = bn + wc * 64 + n * 16 + fr;
        const float s  = S[col];
        const float f  = 128.f - Z[col];
        const float bi = Bias[col];
        #pragma unroll
        for (int m = 0; m < 4; ++m) {
            const long row0 = bm + wr * 64 + m * 16 + (fg << 2);
            #pragma unroll
            for (int r = 0; r < 4; ++r) {
                const float g = (float)acc[m][n][r] + f * sxa[m * 4 + r];
                O[(size_t)(row0 + r) * N_OUT + col] = s * dxa[m * 4 + r] * g + bi;
            }
        }
    }
}

// ---------------- fallback (fused bf16) if ws too small ----------------
__global__ __launch_bounds__(256)
void qlinear_fused(const float* __restrict__ X,
                   const int*   __restrict__ Q,
                   const float* __restrict__ S,
                   const float* __restrict__ Z,
                   const float* __restrict__ Bias,
                   float* __restrict__ O)
{
    __shared__ bf16_t As[128][32];
    __shared__ bf16_t Bs[128][32];
    const int tid = threadIdx.x, lane = tid & 63, wid = tid >> 6;
    const int wr = wid >> 1, wc = wid & 1, fr = lane & 15, fg = lane >> 4;
    const int bm = blockIdx.y * 128, bn = blockIdx.x * 128;
    const int srow = tid >> 1, scol = (tid & 1) << 4;
    const float s_n = S[bn + srow];
    const float zs_n = Z[bn + srow] * s_n;
    const float* xptr = X + (size_t)(bm + srow) * K_IN + scol;
    const int*   qptr = Q + (size_t)(bn + srow) * K_IN + scol;
    f32x4 acc[4][4] = {};
    for (int k0 = 0; k0 < K_IN; k0 += 32) {
        float a[16]; int qi[16];
        { const float4* s4 = (const float4*)(xptr + k0);
          *(float4*)(a+0)=s4[0]; *(float4*)(a+4)=s4[1]; *(float4*)(a+8)=s4[2]; *(float4*)(a+12)=s4[3]; }
        { const int4* s4 = (const int4*)(qptr + k0);
          *(int4*)(qi+0)=s4[0]; *(int4*)(qi+4)=s4[1]; *(int4*)(qi+8)=s4[2]; *(int4*)(qi+12)=s4[3]; }
        float b[16];
        #pragma unroll
        for (int j = 0; j < 16; ++j) b[j] = (float)qi[j] * s_n - zs_n;
        bf16x8 pa0, pa1, pb0, pb1;
        #pragma unroll
        for (int j = 0; j < 8; ++j) {
            pa0[j]=(bf16_t)a[j]; pa1[j]=(bf16_t)a[j+8];
            pb0[j]=(bf16_t)b[j]; pb1[j]=(bf16_t)b[j+8];
        }
        *(bf16x8*)&As[srow][scol]   = pa0; *(bf16x8*)&As[srow][scol+8] = pa1;
        *(bf16x8*)&Bs[srow][scol]   = pb0; *(bf16x8*)&Bs[srow][scol+8] = pb1;
        __syncthreads();
        bf16x8 af[4], bfv[4];
        #pragma unroll
        for (int m = 0; m < 4; ++m) af[m] = *(const bf16x8*)&As[wr*64+m*16+fr][fg*8];
        #pragma unroll
        for (int n = 0; n < 4; ++n) bfv[n] = *(const bf16x8*)&Bs[wc*64+n*16+fr][fg*8];
        #pragma unroll
        for (int m = 0; m < 4; ++m)
            #pragma unroll
            for (int n = 0; n < 4; ++n)
                acc[m][n] = __builtin_amdgcn_mfma_f32_16x16x32_bf16(af[m], bfv[n], acc[m][n], 0,0,0);
        __syncthreads();
    }
    #pragma unroll
    for (int n = 0; n < 4; ++n) {
        const int col = bn + wc*64 + n*16 + fr;
        const float bv = Bias[col];
        #pragma unroll
        for (int m = 0; m < 4; ++m) {
            const int row0 = bm + wr*64 + m*16 + fg*4;
            #pragma unroll
            for (int r = 0; r < 4; ++r)
                O[(size_t)(row0 + r) * N_OUT + col] = acc[m][n][r] + bv;
        }
    }
}

extern "C" void kernel_launch(void* const* d_in, const int* in_sizes, int n_in,
                              void* d_out, int out_size, void* d_ws, size_t ws_size,
                              hipStream_t stream) {
    const float* X    = (const float*)d_in[0];
    const int*   Q    = (const int*)d_in[1];
    const float* S    = (const float*)d_in[2];
    const float* Z    = (const float*)d_in[3];
    const float* Bias = (const float*)d_in[4];
    float* O = (float*)d_out;

    const size_t wbytes = (size_t)N_OUT * K_IN;          // 45,088,768
    const size_t xbytes = (size_t)M_TOK * K_IN;          //  8,388,608
    const size_t need   = wbytes + xbytes + 4 * M_TOK * sizeof(float) + 64;

    if (ws_size >= need) {
        signed char* W8 = (signed char*)d_ws;
        signed char* X8 = (signed char*)d_ws + wbytes;
        float* dxv = (float*)((char*)d_ws + wbytes + xbytes);
        float* sxv = dxv + M_TOK;
        pack_w<<<2048, 256, 0, stream>>>(Q, W8);
        quant_x<<<M_TOK, 256, 0, stream>>>(X, X8, dxv, sxv);
        gemm_i8<<<dim3(688), 512, 0, stream>>>(X8, W8, dxv, sxv, S, Z, Bias, O);
    } else {
        dim3 grid(N_OUT / 128, M_TOK / 128);
        qlinear_fused<<<grid, 256, 0, stream>>>(X, Q, S, Z, Bias, O);
    }
}

// Round 9
// 299.171 us; speedup vs baseline: 3.8038x; 3.8038x over previous
//
#include <hip/hip_runtime.h>
#include <hip/hip_bf16.h>
#include <stdint.h>

typedef __bf16 bf16_t;
typedef bf16_t bf16x8 __attribute__((ext_vector_type(8)));
typedef float  f32x4  __attribute__((ext_vector_type(4)));
typedef int    i32x4  __attribute__((ext_vector_type(4)));

#define M_TOK 2048
#define N_OUT 11008
#define K_IN  4096

#define GLDS16(gptr, lptr)                                                     \
    __builtin_amdgcn_global_load_lds(                                          \
        (__attribute__((address_space(1))) void*)(gptr),                       \
        (__attribute__((address_space(3))) void*)(lptr), 16, 0, 0)

#define VM(N) asm volatile("s_waitcnt vmcnt(" #N ")" ::: "memory")
#define NOP ((void)0)

// ---------------- pre-pass 1: pack W int32 -> i8 (q-128), exact ----------------
__global__ __launch_bounds__(256)
void pack_w(const int* __restrict__ Q, signed char* __restrict__ W8)
{
    const size_t total16 = (size_t)N_OUT * K_IN / 16;
    const size_t stride  = (size_t)gridDim.x * blockDim.x;
    for (size_t i = (size_t)blockIdx.x * blockDim.x + threadIdx.x; i < total16; i += stride) {
        const size_t e0 = i * 16;
        const int4* q4 = (const int4*)(Q + e0);
        unsigned int pk[4];
        #pragma unroll
        for (int j = 0; j < 4; ++j) {
            const int4 q = q4[j];
            pk[j] =  (unsigned int)((q.x - 128) & 255)
                  | ((unsigned int)((q.y - 128) & 255) << 8)
                  | ((unsigned int)((q.z - 128) & 255) << 16)
                  | ((unsigned int)((q.w - 128) & 255) << 24);
        }
        *(int4*)(W8 + e0) = *(const int4*)pk;
    }
}

// ---------------- pre-pass 2: per-token symmetric i8 quant of X ----------------
__global__ __launch_bounds__(256)
void quant_x(const float* __restrict__ X, signed char* __restrict__ X8,
             float* __restrict__ dxv, float* __restrict__ sxv)
{
    const int row = blockIdx.x;
    const int tid = threadIdx.x;
    const float* xr = X + (size_t)row * K_IN + tid * 16;
    float v[16];
    #pragma unroll
    for (int j = 0; j < 4; ++j)
        *(float4*)(v + j * 4) = ((const float4*)xr)[j];

    float amax = 0.f;
    #pragma unroll
    for (int j = 0; j < 16; ++j) amax = fmaxf(amax, fabsf(v[j]));
    #pragma unroll
    for (int m = 1; m < 64; m <<= 1)
        amax = fmaxf(amax, __shfl_xor(amax, m));
    __shared__ float wmax[4];
    __shared__ int   wsum[4];
    const int wv = tid >> 6;
    if ((tid & 63) == 0) wmax[wv] = amax;
    __syncthreads();
    amax = fmaxf(fmaxf(wmax[0], wmax[1]), fmaxf(wmax[2], wmax[3]));
    amax = fmaxf(amax, 1e-20f);
    const float inv = 127.f / amax;

    int sum = 0;
    unsigned int pk[4];
    #pragma unroll
    for (int j = 0; j < 4; ++j) {
        unsigned int p = 0;
        #pragma unroll
        for (int i = 0; i < 4; ++i) {
            int xi = (int)__builtin_rintf(v[j * 4 + i] * inv);
            xi = max(-127, min(127, xi));
            sum += xi;
            p |= ((unsigned int)(xi & 255)) << (8 * i);
        }
        pk[j] = p;
    }
    *(int4*)(X8 + (size_t)row * K_IN + tid * 16) = *(const int4*)pk;

    #pragma unroll
    for (int m = 1; m < 64; m <<= 1) sum += __shfl_xor(sum, m);
    if ((tid & 63) == 0) wsum[wv] = sum;
    __syncthreads();
    if (tid == 0) {
        dxv[row] = amax * (1.f / 127.f);
        sxv[row] = (float)(wsum[0] + wsum[1] + wsum[2] + wsum[3]);
    }
}

// ---------------- main GEMM: i8 128x256, BK=64, B-only LDS (2-buf, 32 KB) ----
// A (X8, 8 MB, L2/L3-resident) is loaded per-wave directly to VGPRs and
// PREFETCHED one K-tile ahead (wave-private regs -> race-free, unlike LDS).
// Region t (between barriers t-1 and t):
//   LOAD_A(tile t+1) -> reg ping-pong   (wave-private; drained by VM(0) below)
//   STAGE_B(tile t+1) -> buf (t+1)&1    (read only at region t+1)
//   ds_read B-frags tile t <- buf t&1
//   16 MFMA (A regs prefetched last region -> zero vmem stall)
//   VM(0); s_barrier                    (own-drain BEFORE barrier: r6 invariant)
// LDS traffic/region: 32 KB reads + 16 KB writes (~500 cyc) < MFMA 653 cyc
// -> MFMA is now the pole. LDS 32 KB never caps residency.

#define ISSUE_B0(SB, KT) GLDS16(gB0 + (KT) * 64, (char*)&sB[SB][0][0] + (tid << 4))
#define ISSUE_B1(SB, KT) GLDS16(gB1 + (KT) * 64, (char*)&sB[SB][0][0] + 8192 + (tid << 4))

#define LOAD_A4(DST, KT) do {                                                  \
    DST##0 = *(const i32x4*)(const void*)(gAd + 0 * 16 * K_IN + (KT) * 64);    \
    DST##1 = *(const i32x4*)(const void*)(gAd + 1 * 16 * K_IN + (KT) * 64);    \
    DST##2 = *(const i32x4*)(const void*)(gAd + 2 * 16 * K_IN + (KT) * 64);    \
    DST##3 = *(const i32x4*)(const void*)(gAd + 3 * 16 * K_IN + (KT) * 64);    \
} while (0)

#define MMROW(FAC, MQ) do {                                                    \
    acc[MQ][0] = __builtin_amdgcn_mfma_i32_16x16x64_i8(FAC##MQ, fb0_, acc[MQ][0], 0, 0, 0); \
    acc[MQ][1] = __builtin_amdgcn_mfma_i32_16x16x64_i8(FAC##MQ, fb1_, acc[MQ][1], 0, 0, 0); \
    acc[MQ][2] = __builtin_amdgcn_mfma_i32_16x16x64_i8(FAC##MQ, fb2_, acc[MQ][2], 0, 0, 0); \
    acc[MQ][3] = __builtin_amdgcn_mfma_i32_16x16x64_i8(FAC##MQ, fb3_, acc[MQ][3], 0, 0, 0); \
} while (0)

#define REGION9(BUFN, STB, FAC, FAN, KTN, STG, BAR) do {                       \
    if (STG) {                                                                 \
        LOAD_A4(FAN, KTN);                                                     \
        ISSUE_B0(STB, KTN); ISSUE_B1(STB, KTN);                                \
    }                                                                          \
    i32x4 fb0_, fb1_, fb2_, fb3_;                                              \
    const char* Bb_ = (const char*)&sB[BUFN][0][0];                            \
    fb0_ = *(const i32x4*)(Bb_ + rowBoff + 0 * 1024 + ckA);                    \
    fb1_ = *(const i32x4*)(Bb_ + rowBoff + 1 * 1024 + ckA);                    \
    fb2_ = *(const i32x4*)(Bb_ + rowBoff + 2 * 1024 + ckA);                    \
    fb3_ = *(const i32x4*)(Bb_ + rowBoff + 3 * 1024 + ckA);                    \
    __builtin_amdgcn_s_setprio(1);                                             \
    MMROW(FAC, 0); MMROW(FAC, 1); MMROW(FAC, 2); MMROW(FAC, 3);                \
    __builtin_amdgcn_s_setprio(0);                                             \
    if (STG) VM(0);                                                            \
    if (BAR) {                                                                 \
        asm volatile("" ::: "memory");                                         \
        __builtin_amdgcn_s_barrier();                                          \
        asm volatile("" ::: "memory");                                         \
    }                                                                          \
} while (0)

__global__ __launch_bounds__(512, 4)
void gemm_i8(const signed char* __restrict__ A8,   // [M_TOK][K_IN] i8
             const signed char* __restrict__ B8,   // [N_OUT][K_IN] i8
             const float* __restrict__ dxv,        // [M_TOK]
             const float* __restrict__ sxv,        // [M_TOK]
             const float* __restrict__ S,
             const float* __restrict__ Z,
             const float* __restrict__ Bias,
             float* __restrict__ O)
{
    __shared__ signed char sB[2][256][64];   // 32 KB total

    const int tid  = threadIdx.x;
    const int lane = tid & 63;
    const int wid  = tid >> 6;
    const int wr   = wid >> 2;   // 0..1  (M half)
    const int wc   = wid & 3;    // 0..3  (N quarter)
    const int fr   = lane & 15;
    const int fg   = lane >> 4;

    // XCD swizzle: 688 = 8 * 86
    const int bid = blockIdx.x;
    const int swz = (bid & 7) * 86 + (bid >> 3);
    const int by  = swz / 43;
    const int bx  = swz - by * 43;
    const long bm = (long)by * 128;
    const long bn = (long)bx * 256;

    // B staging: thread tid -> LDS chunk tid (row tid>>2, chunk tid&3); source
    // holds global chunk (tid&3) ^ ((row>>1)&3). Rows +128 keep same XOR.
    const int srow = tid >> 2;
    const int scg  = ((tid & 3) ^ ((srow >> 1) & 3)) << 4;
    const signed char* gB0 = B8 + (size_t)(bn + srow) * K_IN + scg;
    const signed char* gB1 = B8 + (size_t)(bn + 128 + srow) * K_IN + scg;

    // A direct-from-global: lane (fr,fg) of m-frag MQ reads
    // A8[(bm + wr*64 + MQ*16 + fr)*K + kt*64 + fg*16 .. +16)  (16B aligned)
    const signed char* gAd = A8 + (size_t)(bm + wr * 64 + fr) * K_IN + fg * 16;

    // B ds_read: logical (row, k-chunk fg) at byte row*64 + ((fg^((row>>1)&3))<<4)
    const int ckA     = (fg ^ ((fr >> 1) & 3)) << 4;
    const int rowBoff = (wc * 64 + fr) * 64;

    i32x4 acc[4][4] = {};
    i32x4 faA0, faA1, faA2, faA3;   // A frags, even tiles
    i32x4 faB0, faB1, faB2, faB3;   // A frags, odd tiles

    // prologue: stage B tile0 -> buf0; load A tile0; own-drain; barrier.
    ISSUE_B0(0, 0); ISSUE_B1(0, 0);
    LOAD_A4(faA, 0);
    VM(0);
    asm volatile("" ::: "memory");
    __builtin_amdgcn_s_barrier();
    asm volatile("" ::: "memory");

    // regions t = 0..61 (stage/pref tiles 1..62)
    #pragma unroll 1
    for (int i = 0; i < 31; ++i) {
        REGION9(0, 1, faA, faB, 2 * i + 1, 1, 1);   // t = 2i
        REGION9(1, 0, faB, faA, 2 * i + 2, 1, 1);   // t = 2i+1
    }
    REGION9(0, 1, faA, faB, 63, 1, 1);              // t = 62 (stage/pref tile 63)
    REGION9(1, 0, faB, faA, 0,  0, 0);              // t = 63 (MFMA only)

    // epilogue: y = s*dx*(acc + (128-zp)*sx) + bias
    // C/D: col = lane&15, row = (lane>>4)*4 + reg (shape-determined, verified)
    float dxa[16], sxa[16];
    #pragma unroll
    for (int m = 0; m < 4; ++m)
        #pragma unroll
        for (int r = 0; r < 4; ++r) {
            const int row = (int)bm + wr * 64 + m * 16 + (fg << 2) + r;
            dxa[m * 4 + r] = dxv[row];
            sxa[m * 4 + r] = sxv[row];
        }
    #pragma unroll
    for (int n = 0; n < 4; ++n) {
        const long col = bn + wc * 64 + n * 16 + fr;
        const float s  = S[col];
        const float f  = 128.f - Z[col];
        const float bi = Bias[col];
        #pragma unroll
        for (int m = 0; m < 4; ++m) {
            const long row0 = bm + wr * 64 + m * 16 + (fg << 2);
            #pragma unroll
            for (int r = 0; r < 4; ++r) {
                const float g = (float)acc[m][n][r] + f * sxa[m * 4 + r];
                O[(size_t)(row0 + r) * N_OUT + col] = s * dxa[m * 4 + r] * g + bi;
            }
        }
    }
}

// ---------------- fallback (fused bf16) if ws too small ----------------
__global__ __launch_bounds__(256)
void qlinear_fused(const float* __restrict__ X,
                   const int*   __restrict__ Q,
                   const float* __restrict__ S,
                   const float* __restrict__ Z,
                   const float* __restrict__ Bias,
                   float* __restrict__ O)
{
    __shared__ bf16_t As[128][32];
    __shared__ bf16_t Bs[128][32];
    const int tid = threadIdx.x, lane = tid & 63, wid = tid >> 6;
    const int wr = wid >> 1, wc = wid & 1, fr = lane & 15, fg = lane >> 4;
    const int bm = blockIdx.y * 128, bn = blockIdx.x * 128;
    const int srow = tid >> 1, scol = (tid & 1) << 4;
    const float s_n = S[bn + srow];
    const float zs_n = Z[bn + srow] * s_n;
    const float* xptr = X + (size_t)(bm + srow) * K_IN + scol;
    const int*   qptr = Q + (size_t)(bn + srow) * K_IN + scol;
    f32x4 acc[4][4] = {};
    for (int k0 = 0; k0 < K_IN; k0 += 32) {
        float a[16]; int qi[16];
        { const float4* s4 = (const float4*)(xptr + k0);
          *(float4*)(a+0)=s4[0]; *(float4*)(a+4)=s4[1]; *(float4*)(a+8)=s4[2]; *(float4*)(a+12)=s4[3]; }
        { const int4* s4 = (const int4*)(qptr + k0);
          *(int4*)(qi+0)=s4[0]; *(int4*)(qi+4)=s4[1]; *(int4*)(qi+8)=s4[2]; *(int4*)(qi+12)=s4[3]; }
        float b[16];
        #pragma unroll
        for (int j = 0; j < 16; ++j) b[j] = (float)qi[j] * s_n - zs_n;
        bf16x8 pa0, pa1, pb0, pb1;
        #pragma unroll
        for (int j = 0; j < 8; ++j) {
            pa0[j]=(bf16_t)a[j]; pa1[j]=(bf16_t)a[j+8];
            pb0[j]=(bf16_t)b[j]; pb1[j]=(bf16_t)b[j+8];
        }
        *(bf16x8*)&As[srow][scol]   = pa0; *(bf16x8*)&As[srow][scol+8] = pa1;
        *(bf16x8*)&Bs[srow][scol]   = pb0; *(bf16x8*)&Bs[srow][scol+8] = pb1;
        __syncthreads();
        bf16x8 af[4], bfv[4];
        #pragma unroll
        for (int m = 0; m < 4; ++m) af[m] = *(const bf16x8*)&As[wr*64+m*16+fr][fg*8];
        #pragma unroll
        for (int n = 0; n < 4; ++n) bfv[n] = *(const bf16x8*)&Bs[wc*64+n*16+fr][fg*8];
        #pragma unroll
        for (int m = 0; m < 4; ++m)
            #pragma unroll
            for (int n = 0; n < 4; ++n)
                acc[m][n] = __builtin_amdgcn_mfma_f32_16x16x32_bf16(af[m], bfv[n], acc[m][n], 0,0,0);
        __syncthreads();
    }
    #pragma unroll
    for (int n = 0; n < 4; ++n) {
        const int col = bn + wc*64 + n*16 + fr;
        const float bv = Bias[col];
        #pragma unroll
        for (int m = 0; m < 4; ++m) {
            const int row0 = bm + wr*64 + m*16 + fg*4;
            #pragma unroll
            for (int r = 0; r < 4; ++r)
                O[(size_t)(row0 + r) * N_OUT + col] = acc[m][n][r] + bv;
        }
    }
}

extern "C" void kernel_launch(void* const* d_in, const int* in_sizes, int n_in,
                              void* d_out, int out_size, void* d_ws, size_t ws_size,
                              hipStream_t stream) {
    const float* X    = (const float*)d_in[0];
    const int*   Q    = (const int*)d_in[1];
    const float* S    = (const float*)d_in[2];
    const float* Z    = (const float*)d_in[3];
    const float* Bias = (const float*)d_in[4];
    float* O = (float*)d_out;

    const size_t wbytes = (size_t)N_OUT * K_IN;          // 45,088,768
    const size_t xbytes = (size_t)M_TOK * K_IN;          //  8,388,608
    const size_t need   = wbytes + xbytes + 4 * M_TOK * sizeof(float) + 64;

    if (ws_size >= need) {
        signed char* W8 = (signed char*)d_ws;
        signed char* X8 = (signed char*)d_ws + wbytes;
        float* dxv = (float*)((char*)d_ws + wbytes + xbytes);
        float* sxv = dxv + M_TOK;
        pack_w<<<2048, 256, 0, stream>>>(Q, W8);
        quant_x<<<M_TOK, 256, 0, stream>>>(X, X8, dxv, sxv);
        gemm_i8<<<dim3(688), 512, 0, stream>>>(X8, W8, dxv, sxv, S, Z, Bias, O);
    } else {
        dim3 grid(N_OUT / 128, M_TOK / 128);
        qlinear_fused<<<grid, 256, 0, stream>>>(X, Q, S, Z, Bias, O);
    }
}

// Round 10
// 290.313 us; speedup vs baseline: 3.9199x; 1.0305x over previous
//
#include <hip/hip_runtime.h>
#include <hip/hip_bf16.h>
#include <stdint.h>

typedef __bf16 bf16_t;
typedef bf16_t bf16x8 __attribute__((ext_vector_type(8)));
typedef float  f32x4  __attribute__((ext_vector_type(4)));
typedef int    i32x4  __attribute__((ext_vector_type(4)));

#define M_TOK 2048
#define N_OUT 11008
#define K_IN  4096

#define GLDS16(gptr, lptr)                                                     \
    __builtin_amdgcn_global_load_lds(                                          \
        (__attribute__((address_space(1))) void*)(gptr),                       \
        (__attribute__((address_space(3))) void*)(lptr), 16, 0, 0)

#define VM(N) asm volatile("s_waitcnt vmcnt(" #N ")" ::: "memory")
#define NOP ((void)0)

// ---------------- pre-pass 1: pack W int32 -> i8 (q-128), exact ----------------
__global__ __launch_bounds__(256)
void pack_w(const int* __restrict__ Q, signed char* __restrict__ W8)
{
    const size_t total16 = (size_t)N_OUT * K_IN / 16;
    const size_t stride  = (size_t)gridDim.x * blockDim.x;
    for (size_t i = (size_t)blockIdx.x * blockDim.x + threadIdx.x; i < total16; i += stride) {
        const size_t e0 = i * 16;
        const int4* q4 = (const int4*)(Q + e0);
        unsigned int pk[4];
        #pragma unroll
        for (int j = 0; j < 4; ++j) {
            const int4 q = q4[j];
            pk[j] =  (unsigned int)((q.x - 128) & 255)
                  | ((unsigned int)((q.y - 128) & 255) << 8)
                  | ((unsigned int)((q.z - 128) & 255) << 16)
                  | ((unsigned int)((q.w - 128) & 255) << 24);
        }
        *(int4*)(W8 + e0) = *(const int4*)pk;
    }
}

// ---------------- pre-pass 2: per-token symmetric i8 quant of X ----------------
__global__ __launch_bounds__(256)
void quant_x(const float* __restrict__ X, signed char* __restrict__ X8,
             float* __restrict__ dxv, float* __restrict__ sxv)
{
    const int row = blockIdx.x;
    const int tid = threadIdx.x;
    const float* xr = X + (size_t)row * K_IN + tid * 16;
    float v[16];
    #pragma unroll
    for (int j = 0; j < 4; ++j)
        *(float4*)(v + j * 4) = ((const float4*)xr)[j];

    float amax = 0.f;
    #pragma unroll
    for (int j = 0; j < 16; ++j) amax = fmaxf(amax, fabsf(v[j]));
    #pragma unroll
    for (int m = 1; m < 64; m <<= 1)
        amax = fmaxf(amax, __shfl_xor(amax, m));
    __shared__ float wmax[4];
    __shared__ int   wsum[4];
    const int wv = tid >> 6;
    if ((tid & 63) == 0) wmax[wv] = amax;
    __syncthreads();
    amax = fmaxf(fmaxf(wmax[0], wmax[1]), fmaxf(wmax[2], wmax[3]));
    amax = fmaxf(amax, 1e-20f);
    const float inv = 127.f / amax;

    int sum = 0;
    unsigned int pk[4];
    #pragma unroll
    for (int j = 0; j < 4; ++j) {
        unsigned int p = 0;
        #pragma unroll
        for (int i = 0; i < 4; ++i) {
            int xi = (int)__builtin_rintf(v[j * 4 + i] * inv);
            xi = max(-127, min(127, xi));
            sum += xi;
            p |= ((unsigned int)(xi & 255)) << (8 * i);
        }
        pk[j] = p;
    }
    *(int4*)(X8 + (size_t)row * K_IN + tid * 16) = *(const int4*)pk;

    #pragma unroll
    for (int m = 1; m < 64; m <<= 1) sum += __shfl_xor(sum, m);
    if ((tid & 63) == 0) wsum[wv] = sum;
    __syncthreads();
    if (tid == 0) {
        dxv[row] = amax * (1.f / 127.f);
        sxv[row] = (float)(wsum[0] + wsum[1] + wsum[2] + wsum[3]);
    }
}

// ---------------- main GEMM: i8 128x256, BK=64, A-in-reg + B 3-buf LDS -------
// Region t (between barriers t-1 and t):
//   ISSUE B(t+2) -> buf (t+2)%3          [2x global_load_lds, FIRST in queue]
//   LOAD  A(t+1) -> reg ping-pong        [4x dwordx4, wave-private: race-free]
//   ds_read B(t) frags <- buf t%3
//   16 MFMA (A(t) regs; compiler auto-inserts vmcnt<=6 before first use,
//            which ALSO forces the older B(t+1) loads complete -> the
//            drain-before-barrier invariant holds by construction)
//   VM(6)  [defense-in-depth: newest 6 = B(t+2)+A(t+1) may stay in flight]
//   s_barrier
// 3-buf write hazard: B(t+2) targets buf (t-1)%3, last read region t-1 before
// barrier t-1; writes issued after barrier t-1 -> safe.
// XCD map: XCD x owns bn-cols 5x..5x+4 (16 co-resident same-col blocks ->
// W-panel L2-hit) + 6 tiles of cols 40..42. W HBM ~67MB vs 360MB round-robin.

#define ISSUE_B0(SB, KT) GLDS16(gB0 + (KT) * 64, (char*)&sB[SB][0][0] + (tid << 4))
#define ISSUE_B1(SB, KT) GLDS16(gB1 + (KT) * 64, (char*)&sB[SB][0][0] + 8192 + (tid << 4))

#define LOAD_A4(DST, KT) do {                                                  \
    DST##0 = *(const i32x4*)(const void*)(gAd + 0 * 16 * K_IN + (KT) * 64);    \
    DST##1 = *(const i32x4*)(const void*)(gAd + 1 * 16 * K_IN + (KT) * 64);    \
    DST##2 = *(const i32x4*)(const void*)(gAd + 2 * 16 * K_IN + (KT) * 64);    \
    DST##3 = *(const i32x4*)(const void*)(gAd + 3 * 16 * K_IN + (KT) * 64);    \
} while (0)

#define MMROW(FAC, MQ) do {                                                    \
    acc[MQ][0] = __builtin_amdgcn_mfma_i32_16x16x64_i8(FAC##MQ, fb0_, acc[MQ][0], 0, 0, 0); \
    acc[MQ][1] = __builtin_amdgcn_mfma_i32_16x16x64_i8(FAC##MQ, fb1_, acc[MQ][1], 0, 0, 0); \
    acc[MQ][2] = __builtin_amdgcn_mfma_i32_16x16x64_i8(FAC##MQ, fb2_, acc[MQ][2], 0, 0, 0); \
    acc[MQ][3] = __builtin_amdgcn_mfma_i32_16x16x64_i8(FAC##MQ, fb3_, acc[MQ][3], 0, 0, 0); \
} while (0)

// DOB: stage B(KTB) into STB.  DOA: load A(KTA) into FAN.  WMODE 0:VM(6)+bar,
// 1:VM(0)+bar, 2: nothing (final region).
#define REGION10(BUFN, STB, FAC, FAN, KTB, KTA, DOB, DOA, WMODE) do {          \
    if (DOB) { ISSUE_B0(STB, KTB); ISSUE_B1(STB, KTB); }                       \
    if (DOA) { LOAD_A4(FAN, KTA); }                                            \
    i32x4 fb0_, fb1_, fb2_, fb3_;                                              \
    const char* Bb_ = (const char*)&sB[BUFN][0][0];                            \
    fb0_ = *(const i32x4*)(Bb_ + rowBoff + 0 * 1024 + ckA);                    \
    fb1_ = *(const i32x4*)(Bb_ + rowBoff + 1 * 1024 + ckA);                    \
    fb2_ = *(const i32x4*)(Bb_ + rowBoff + 2 * 1024 + ckA);                    \
    fb3_ = *(const i32x4*)(Bb_ + rowBoff + 3 * 1024 + ckA);                    \
    __builtin_amdgcn_s_setprio(1);                                             \
    MMROW(FAC, 0); MMROW(FAC, 1); MMROW(FAC, 2); MMROW(FAC, 3);                \
    __builtin_amdgcn_s_setprio(0);                                             \
    if ((WMODE) == 0) VM(6);                                                   \
    if ((WMODE) == 1) VM(0);                                                   \
    if ((WMODE) != 2) {                                                        \
        asm volatile("" ::: "memory");                                         \
        __builtin_amdgcn_s_barrier();                                          \
        asm volatile("" ::: "memory");                                         \
    }                                                                          \
} while (0)

__global__ __launch_bounds__(512, 4)
void gemm_i8(const signed char* __restrict__ A8,   // [M_TOK][K_IN] i8
             const signed char* __restrict__ B8,   // [N_OUT][K_IN] i8
             const float* __restrict__ dxv,        // [M_TOK]
             const float* __restrict__ sxv,        // [M_TOK]
             const float* __restrict__ S,
             const float* __restrict__ Z,
             const float* __restrict__ Bias,
             float* __restrict__ O)
{
    __shared__ signed char sB[3][256][64];   // 48 KB

    const int tid  = threadIdx.x;
    const int lane = tid & 63;
    const int wid  = tid >> 6;
    const int wr   = wid >> 2;   // 0..1  (M half)
    const int wc   = wid & 3;    // 0..3  (N quarter)
    const int fr   = lane & 15;
    const int fg   = lane >> 4;

    // XCD partition: xcd = bid&7 owns 86 tiles: cols 5x..5x+4 x 16 by (80)
    // + 6 tiles of cols 40..42 (by = 2x, 2x+1). Bijective over 43x16.
    const int bid = blockIdx.x;
    const int xcd = bid & 7;
    const int k   = bid >> 3;           // 0..85
    int col, by;
    if (k < 80) { col = 5 * xcd + (k >> 4); by = k & 15; }
    else        { const int e = k - 80; col = 40 + (e >> 1); by = 2 * xcd + (e & 1); }
    const long bm = (long)by * 128;
    const long bn = (long)col * 256;

    // B staging: thread tid -> LDS chunk tid (row tid>>2, chunk tid&3); source
    // holds global chunk (tid&3) ^ ((row>>1)&3). Rows +128 keep same XOR.
    const int srow = tid >> 2;
    const int scg  = ((tid & 3) ^ ((srow >> 1) & 3)) << 4;
    const signed char* gB0 = B8 + (size_t)(bn + srow) * K_IN + scg;
    const signed char* gB1 = B8 + (size_t)(bn + 128 + srow) * K_IN + scg;

    // A direct-from-global: lane (fr,fg) of m-frag MQ reads
    // A8[(bm + wr*64 + MQ*16 + fr)*K + kt*64 + fg*16 .. +16)
    const signed char* gAd = A8 + (size_t)(bm + wr * 64 + fr) * K_IN + fg * 16;

    // B ds_read: logical (row, k-chunk fg) at byte row*64 + ((fg^((row>>1)&3))<<4)
    const int ckA     = (fg ^ ((fr >> 1) & 3)) << 4;
    const int rowBoff = (wc * 64 + fr) * 64;

    i32x4 acc[4][4] = {};
    i32x4 faA0, faA1, faA2, faA3;   // A frags, even tiles
    i32x4 faB0, faB1, faB2, faB3;   // A frags, odd tiles

    // prologue: stage B(0)->buf0, B(1)->buf1 (B FIRST in vmem queue), A(0).
    // VM(6) drains the two oldest ops = B(0). barrier.
    ISSUE_B0(0, 0); ISSUE_B1(0, 0);
    ISSUE_B0(1, 1); ISSUE_B1(1, 1);
    LOAD_A4(faA, 0);
    VM(6);
    asm volatile("" ::: "memory");
    __builtin_amdgcn_s_barrier();
    asm volatile("" ::: "memory");

    // regions t = 0..59: 6-region bodies (3 bufs x 2 A-parities)
    #pragma unroll 1
    for (int i = 0; i < 10; ++i) {
        const int t = i * 6;
        REGION10(0, 2, faA, faB, t + 2, t + 1, 1, 1, 0);   // t+0
        REGION10(1, 0, faB, faA, t + 3, t + 2, 1, 1, 0);   // t+1
        REGION10(2, 1, faA, faB, t + 4, t + 3, 1, 1, 0);   // t+2
        REGION10(0, 2, faB, faA, t + 5, t + 4, 1, 1, 0);   // t+3
        REGION10(1, 0, faA, faB, t + 6, t + 5, 1, 1, 0);   // t+4
        REGION10(2, 1, faB, faA, t + 7, t + 6, 1, 1, 0);   // t+5
    }
    REGION10(0, 2, faA, faB, 62, 61, 1, 1, 0);   // t=60: stage B62, A61
    REGION10(1, 0, faB, faA, 63, 62, 1, 1, 0);   // t=61: stage B63, A62
    REGION10(2, 0, faA, faB,  0, 63, 0, 1, 1);   // t=62: A63 only; VM(0)
    REGION10(0, 0, faB, faA,  0,  0, 0, 0, 2);   // t=63: MFMA only

    // epilogue: y = s*dx*(acc + (128-zp)*sx) + bias
    // C/D: col = lane&15, row = (lane>>4)*4 + reg (shape-determined, verified)
    float dxa[16], sxa[16];
    #pragma unroll
    for (int m = 0; m < 4; ++m)
        #pragma unroll
        for (int r = 0; r < 4; ++r) {
            const int row = (int)bm + wr * 64 + m * 16 + (fg << 2) + r;
            dxa[m * 4 + r] = dxv[row];
            sxa[m * 4 + r] = sxv[row];
        }
    #pragma unroll
    for (int n = 0; n < 4; ++n) {
        const long ocol = bn + wc * 64 + n * 16 + fr;
        const float s  = S[ocol];
        const float f  = 128.f - Z[ocol];
        const float bi = Bias[ocol];
        #pragma unroll
        for (int m = 0; m < 4; ++m) {
            const long row0 = bm + wr * 64 + m * 16 + (fg << 2);
            #pragma unroll
            for (int r = 0; r < 4; ++r) {
                const float g = (float)acc[m][n][r] + f * sxa[m * 4 + r];
                O[(size_t)(row0 + r) * N_OUT + ocol] = s * dxa[m * 4 + r] * g + bi;
            }
        }
    }
}

// ---------------- fallback (fused bf16) if ws too small ----------------
__global__ __launch_bounds__(256)
void qlinear_fused(const float* __restrict__ X,
                   const int*   __restrict__ Q,
                   const float* __restrict__ S,
                   const float* __restrict__ Z,
                   const float* __restrict__ Bias,
                   float* __restrict__ O)
{
    __shared__ bf16_t As[128][32];
    __shared__ bf16_t Bs[128][32];
    const int tid = threadIdx.x, lane = tid & 63, wid = tid >> 6;
    const int wr = wid >> 1, wc = wid & 1, fr = lane & 15, fg = lane >> 4;
    const int bm = blockIdx.y * 128, bn = blockIdx.x * 128;
    const int srow = tid >> 1, scol = (tid & 1) << 4;
    const float s_n = S[bn + srow];
    const float zs_n = Z[bn + srow] * s_n;
    const float* xptr = X + (size_t)(bm + srow) * K_IN + scol;
    const int*   qptr = Q + (size_t)(bn + srow) * K_IN + scol;
    f32x4 acc[4][4] = {};
    for (int k0 = 0; k0 < K_IN; k0 += 32) {
        float a[16]; int qi[16];
        { const float4* s4 = (const float4*)(xptr + k0);
          *(float4*)(a+0)=s4[0]; *(float4*)(a+4)=s4[1]; *(float4*)(a+8)=s4[2]; *(float4*)(a+12)=s4[3]; }
        { const int4* s4 = (const int4*)(qptr + k0);
          *(int4*)(qi+0)=s4[0]; *(int4*)(qi+4)=s4[1]; *(int4*)(qi+8)=s4[2]; *(int4*)(qi+12)=s4[3]; }
        float b[16];
        #pragma unroll
        for (int j = 0; j < 16; ++j) b[j] = (float)qi[j] * s_n - zs_n;
        bf16x8 pa0, pa1, pb0, pb1;
        #pragma unroll
        for (int j = 0; j < 8; ++j) {
            pa0[j]=(bf16_t)a[j]; pa1[j]=(bf16_t)a[j+8];
            pb0[j]=(bf16_t)b[j]; pb1[j]=(bf16_t)b[j+8];
        }
        *(bf16x8*)&As[srow][scol]   = pa0; *(bf16x8*)&As[srow][scol+8] = pa1;
        *(bf16x8*)&Bs[srow][scol]   = pb0; *(bf16x8*)&Bs[srow][scol+8] = pb1;
        __syncthreads();
        bf16x8 af[4], bfv[4];
        #pragma unroll
        for (int m = 0; m < 4; ++m) af[m] = *(const bf16x8*)&As[wr*64+m*16+fr][fg*8];
        #pragma unroll
        for (int n = 0; n < 4; ++n) bfv[n] = *(const bf16x8*)&Bs[wc*64+n*16+fr][fg*8];
        #pragma unroll
        for (int m = 0; m < 4; ++m)
            #pragma unroll
            for (int n = 0; n < 4; ++n)
                acc[m][n] = __builtin_amdgcn_mfma_f32_16x16x32_bf16(af[m], bfv[n], acc[m][n], 0,0,0);
        __syncthreads();
    }
    #pragma unroll
    for (int n = 0; n < 4; ++n) {
        const int col = bn + wc*64 + n*16 + fr;
        const float bv = Bias[col];
        #pragma unroll
        for (int m = 0; m < 4; ++m) {
            const int row0 = bm + wr*64 + m*16 + fg*4;
            #pragma unroll
            for (int r = 0; r < 4; ++r)
                O[(size_t)(row0 + r) * N_OUT + col] = acc[m][n][r] + bv;
        }
    }
}

extern "C" void kernel_launch(void* const* d_in, const int* in_sizes, int n_in,
                              void* d_out, int out_size, void* d_ws, size_t ws_size,
                              hipStream_t stream) {
    const float* X    = (const float*)d_in[0];
    const int*   Q    = (const int*)d_in[1];
    const float* S    = (const float*)d_in[2];
    const float* Z    = (const float*)d_in[3];
    const float* Bias = (const float*)d_in[4];
    float* O = (float*)d_out;

    const size_t wbytes = (size_t)N_OUT * K_IN;          // 45,088,768
    const size_t xbytes = (size_t)M_TOK * K_IN;          //  8,388,608
    const size_t need   = wbytes + xbytes + 4 * M_TOK * sizeof(float) + 64;

    if (ws_size >= need) {
        signed char* W8 = (signed char*)d_ws;
        signed char* X8 = (signed char*)d_ws + wbytes;
        float* dxv = (float*)((char*)d_ws + wbytes + xbytes);
        float* sxv = dxv + M_TOK;
        pack_w<<<2048, 256, 0, stream>>>(Q, W8);
        quant_x<<<M_TOK, 256, 0, stream>>>(X, X8, dxv, sxv);
        gemm_i8<<<dim3(688), 512, 0, stream>>>(X8, W8, dxv, sxv, S, Z, Bias, O);
    } else {
        dim3 grid(N_OUT / 128, M_TOK / 128);
        qlinear_fused<<<grid, 256, 0, stream>>>(X, Q, S, Z, Bias, O);
    }
}

// Round 11
// 213.426 us; speedup vs baseline: 5.3320x; 1.3602x over previous
//
#include <hip/hip_runtime.h>
#include <hip/hip_bf16.h>
#include <stdint.h>

typedef __bf16 bf16_t;
typedef bf16_t bf16x8 __attribute__((ext_vector_type(8)));
typedef float  f32x4  __attribute__((ext_vector_type(4)));
typedef int    i32x4  __attribute__((ext_vector_type(4)));

#define M_TOK 2048
#define N_OUT 11008
#define K_IN  4096

#define GLDS16(gptr, lptr)                                                     \
    __builtin_amdgcn_global_load_lds(                                          \
        (__attribute__((address_space(1))) void*)(gptr),                       \
        (__attribute__((address_space(3))) void*)(lptr), 16, 0, 0)

#define VM(N) asm volatile("s_waitcnt vmcnt(" #N ")" ::: "memory")
#define NOP ((void)0)

// ---------------- pre-pass 1: pack W int32 -> i8 (q-128), exact ----------------
__global__ __launch_bounds__(256)
void pack_w(const int* __restrict__ Q, signed char* __restrict__ W8)
{
    const size_t total16 = (size_t)N_OUT * K_IN / 16;
    const size_t stride  = (size_t)gridDim.x * blockDim.x;
    for (size_t i = (size_t)blockIdx.x * blockDim.x + threadIdx.x; i < total16; i += stride) {
        const size_t e0 = i * 16;
        const int4* q4 = (const int4*)(Q + e0);
        unsigned int pk[4];
        #pragma unroll
        for (int j = 0; j < 4; ++j) {
            const int4 q = q4[j];
            pk[j] =  (unsigned int)((q.x - 128) & 255)
                  | ((unsigned int)((q.y - 128) & 255) << 8)
                  | ((unsigned int)((q.z - 128) & 255) << 16)
                  | ((unsigned int)((q.w - 128) & 255) << 24);
        }
        *(int4*)(W8 + e0) = *(const int4*)pk;
    }
}

// -------- pre-pass 2: per-token symmetric i8 quant of X, FRAGMENT-LINEAR -----
// X8t layout: element (row m, k) at byte ((kt*128 + m16)*64 + fg*16 + fr)*16 + j
// where kt=k>>6, fg=(k>>4)&3, j=k&15, m16=m>>4, fr=m&15.
// => a wave's A-frag (m-frag MQ, K-tile kt) is ONE contiguous 1KB load at
//    base + lane*16 (lane = fg*16+fr), fully coalesced.
__global__ __launch_bounds__(256)
void quant_x(const float* __restrict__ X, signed char* __restrict__ X8,
             float* __restrict__ dxv, float* __restrict__ sxv)
{
    const int row = blockIdx.x;
    const int tid = threadIdx.x;
    const float* xr = X + (size_t)row * K_IN + tid * 16;
    float v[16];
    #pragma unroll
    for (int j = 0; j < 4; ++j)
        *(float4*)(v + j * 4) = ((const float4*)xr)[j];

    float amax = 0.f;
    #pragma unroll
    for (int j = 0; j < 16; ++j) amax = fmaxf(amax, fabsf(v[j]));
    #pragma unroll
    for (int m = 1; m < 64; m <<= 1)
        amax = fmaxf(amax, __shfl_xor(amax, m));
    __shared__ float wmax[4];
    __shared__ int   wsum[4];
    const int wv = tid >> 6;
    if ((tid & 63) == 0) wmax[wv] = amax;
    __syncthreads();
    amax = fmaxf(fmaxf(wmax[0], wmax[1]), fmaxf(wmax[2], wmax[3]));
    amax = fmaxf(amax, 1e-20f);
    const float inv = 127.f / amax;

    int sum = 0;
    unsigned int pk[4];
    #pragma unroll
    for (int j = 0; j < 4; ++j) {
        unsigned int p = 0;
        #pragma unroll
        for (int i = 0; i < 4; ++i) {
            int xi = (int)__builtin_rintf(v[j * 4 + i] * inv);
            xi = max(-127, min(127, xi));
            sum += xi;
            p |= ((unsigned int)(xi & 255)) << (8 * i);
        }
        pk[j] = p;
    }
    // transposed store: this thread's 16 k-bytes = one fragment 16B chunk
    const size_t toff = (((size_t)(tid >> 2) * 128 + (row >> 4)) * 64
                         + (size_t)((tid & 3) * 16 + (row & 15))) * 16;
    *(int4*)(X8 + toff) = *(const int4*)pk;

    #pragma unroll
    for (int m = 1; m < 64; m <<= 1) sum += __shfl_xor(sum, m);
    if ((tid & 63) == 0) wsum[wv] = sum;
    __syncthreads();
    if (tid == 0) {
        dxv[row] = amax * (1.f / 127.f);
        sxv[row] = (float)(wsum[0] + wsum[1] + wsum[2] + wsum[3]);
    }
}

// ---------------- main GEMM: i8 128x256, BK=64, A-direct(coalesced) + B 3-buf
// Region t (between barriers t-1 and t):
//   ISSUE B(t+2) -> buf (t+2)%3          [2x global_load_lds, FIRST in queue]
//   LOAD  A(t+1) -> reg ping-pong        [4x coalesced 1KB dwordx4, wave-private]
//   ds_read B(t) frags <- buf t%3
//   16 MFMA (A(t) regs; compiler auto-waits vmcnt<=6 before first use, which
//            also forces the older B(t+1) loads complete before the barrier)
//   VM(6); s_barrier                     [drain-own-before-barrier invariant]
// LDS/CU-region = B-only 96KB (~1020cyc) < MFMA (1306cyc) -> MFMA-bound.
// XCD map: XCD x owns bn-cols 5x..5x+4 (16 co-resident same-col blocks) + 6
// spill tiles of cols 40..42; bijective over 43x16. FETCH ~142MB (measured r10).

#define ISSUE_B0(SB, KT) GLDS16(gB0 + (KT) * 64, (char*)&sB[SB][0][0] + (tid << 4))
#define ISSUE_B1(SB, KT) GLDS16(gB1 + (KT) * 64, (char*)&sB[SB][0][0] + 8192 + (tid << 4))

#define LOAD_A4(DST, KT) do {                                                  \
    const char* ap_ = gAt + (size_t)(KT) * 131072;                             \
    DST##0 = *(const i32x4*)(ap_ + 0 * 1024);                                  \
    DST##1 = *(const i32x4*)(ap_ + 1 * 1024);                                  \
    DST##2 = *(const i32x4*)(ap_ + 2 * 1024);                                  \
    DST##3 = *(const i32x4*)(ap_ + 3 * 1024);                                  \
} while (0)

#define MMROW(FAC, MQ) do {                                                    \
    acc[MQ][0] = __builtin_amdgcn_mfma_i32_16x16x64_i8(FAC##MQ, fb0_, acc[MQ][0], 0, 0, 0); \
    acc[MQ][1] = __builtin_amdgcn_mfma_i32_16x16x64_i8(FAC##MQ, fb1_, acc[MQ][1], 0, 0, 0); \
    acc[MQ][2] = __builtin_amdgcn_mfma_i32_16x16x64_i8(FAC##MQ, fb2_, acc[MQ][2], 0, 0, 0); \
    acc[MQ][3] = __builtin_amdgcn_mfma_i32_16x16x64_i8(FAC##MQ, fb3_, acc[MQ][3], 0, 0, 0); \
} while (0)

// DOB: stage B(KTB) into STB.  DOA: load A(KTA) into FAN.  WMODE 0:VM(6)+bar,
// 1:VM(0)+bar, 2: nothing (final region).
#define REGION11(BUFN, STB, FAC, FAN, KTB, KTA, DOB, DOA, WMODE) do {          \
    if (DOB) { ISSUE_B0(STB, KTB); ISSUE_B1(STB, KTB); }                       \
    if (DOA) { LOAD_A4(FAN, KTA); }                                            \
    i32x4 fb0_, fb1_, fb2_, fb3_;                                              \
    const char* Bb_ = (const char*)&sB[BUFN][0][0];                            \
    fb0_ = *(const i32x4*)(Bb_ + rowBoff + 0 * 1024 + ckA);                    \
    fb1_ = *(const i32x4*)(Bb_ + rowBoff + 1 * 1024 + ckA);                    \
    fb2_ = *(const i32x4*)(Bb_ + rowBoff + 2 * 1024 + ckA);                    \
    fb3_ = *(const i32x4*)(Bb_ + rowBoff + 3 * 1024 + ckA);                    \
    __builtin_amdgcn_s_setprio(1);                                             \
    MMROW(FAC, 0); MMROW(FAC, 1); MMROW(FAC, 2); MMROW(FAC, 3);                \
    __builtin_amdgcn_s_setprio(0);                                             \
    if ((WMODE) == 0) VM(6);                                                   \
    if ((WMODE) == 1) VM(0);                                                   \
    if ((WMODE) != 2) {                                                        \
        asm volatile("" ::: "memory");                                         \
        __builtin_amdgcn_s_barrier();                                          \
        asm volatile("" ::: "memory");                                         \
    }                                                                          \
} while (0)

__global__ __launch_bounds__(512, 4)
void gemm_i8(const signed char* __restrict__ A8t,  // X8 fragment-linear (8 MB)
             const signed char* __restrict__ B8,   // [N_OUT][K_IN] i8
             const float* __restrict__ dxv,        // [M_TOK]
             const float* __restrict__ sxv,        // [M_TOK]
             const float* __restrict__ S,
             const float* __restrict__ Z,
             const float* __restrict__ Bias,
             float* __restrict__ O)
{
    __shared__ signed char sB[3][256][64];   // 48 KB

    const int tid  = threadIdx.x;
    const int lane = tid & 63;
    const int wid  = tid >> 6;
    const int wr   = wid >> 2;   // 0..1  (M half)
    const int wc   = wid & 3;    // 0..3  (N quarter)
    const int fr   = lane & 15;
    const int fg   = lane >> 4;

    // XCD partition: xcd = bid&7 owns 86 tiles: cols 5x..5x+4 x 16 by (80)
    // + 6 tiles of cols 40..42 (by = 2x, 2x+1). Bijective over 43x16.
    const int bid = blockIdx.x;
    const int xcd = bid & 7;
    const int k   = bid >> 3;           // 0..85
    int col, by;
    if (k < 80) { col = 5 * xcd + (k >> 4); by = k & 15; }
    else        { const int e = k - 80; col = 40 + (e >> 1); by = 2 * xcd + (e & 1); }
    const long bm = (long)by * 128;
    const long bn = (long)col * 256;

    // B staging: thread tid -> LDS chunk tid (row tid>>2, chunk tid&3); source
    // holds global chunk (tid&3) ^ ((row>>1)&3). Rows +128 keep same XOR.
    const int srow = tid >> 2;
    const int scg  = ((tid & 3) ^ ((srow >> 1) & 3)) << 4;
    const signed char* gB0 = B8 + (size_t)(bn + srow) * K_IN + scg;
    const signed char* gB1 = B8 + (size_t)(bn + 128 + srow) * K_IN + scg;

    // A fragment-linear base: frag (kt, MQ) = 1KB at
    //   A8t + (kt*128 + by*8 + wr*4 + MQ)*1024 + lane*16
    const char* gAt = (const char*)A8t
                    + (((size_t)(by * 8 + wr * 4) * 64) + lane) * 16;

    // B ds_read: logical (row, k-chunk fg) at byte row*64 + ((fg^((row>>1)&3))<<4)
    const int ckA     = (fg ^ ((fr >> 1) & 3)) << 4;
    const int rowBoff = (wc * 64 + fr) * 64;

    i32x4 acc[4][4] = {};
    i32x4 faA0, faA1, faA2, faA3;   // A frags, even tiles
    i32x4 faB0, faB1, faB2, faB3;   // A frags, odd tiles

    // prologue: stage B(0)->buf0, B(1)->buf1 (B FIRST in vmem queue), A(0).
    // VM(6) drains the two oldest ops = B(0). barrier.
    ISSUE_B0(0, 0); ISSUE_B1(0, 0);
    ISSUE_B0(1, 1); ISSUE_B1(1, 1);
    LOAD_A4(faA, 0);
    VM(6);
    asm volatile("" ::: "memory");
    __builtin_amdgcn_s_barrier();
    asm volatile("" ::: "memory");

    // regions t = 0..59: 6-region bodies (3 bufs x 2 A-parities)
    #pragma unroll 1
    for (int i = 0; i < 10; ++i) {
        const int t = i * 6;
        REGION11(0, 2, faA, faB, t + 2, t + 1, 1, 1, 0);   // t+0
        REGION11(1, 0, faB, faA, t + 3, t + 2, 1, 1, 0);   // t+1
        REGION11(2, 1, faA, faB, t + 4, t + 3, 1, 1, 0);   // t+2
        REGION11(0, 2, faB, faA, t + 5, t + 4, 1, 1, 0);   // t+3
        REGION11(1, 0, faA, faB, t + 6, t + 5, 1, 1, 0);   // t+4
        REGION11(2, 1, faB, faA, t + 7, t + 6, 1, 1, 0);   // t+5
    }
    REGION11(0, 2, faA, faB, 62, 61, 1, 1, 0);   // t=60: stage B62, A61
    REGION11(1, 0, faB, faA, 63, 62, 1, 1, 0);   // t=61: stage B63, A62
    REGION11(2, 0, faA, faB,  0, 63, 0, 1, 1);   // t=62: A63 only; VM(0)
    REGION11(0, 0, faB, faA,  0,  0, 0, 0, 2);   // t=63: MFMA only

    // epilogue: y = s*dx*(acc + (128-zp)*sx) + bias
    // C/D: col = lane&15, row = (lane>>4)*4 + reg (shape-determined, verified)
    float dxa[16], sxa[16];
    #pragma unroll
    for (int m = 0; m < 4; ++m)
        #pragma unroll
        for (int r = 0; r < 4; ++r) {
            const int row = (int)bm + wr * 64 + m * 16 + (fg << 2) + r;
            dxa[m * 4 + r] = dxv[row];
            sxa[m * 4 + r] = sxv[row];
        }
    #pragma unroll
    for (int n = 0; n < 4; ++n) {
        const long ocol = bn + wc * 64 + n * 16 + fr;
        const float s  = S[ocol];
        const float f  = 128.f - Z[ocol];
        const float bi = Bias[ocol];
        #pragma unroll
        for (int m = 0; m < 4; ++m) {
            const long row0 = bm + wr * 64 + m * 16 + (fg << 2);
            #pragma unroll
            for (int r = 0; r < 4; ++r) {
                const float g = (float)acc[m][n][r] + f * sxa[m * 4 + r];
                O[(size_t)(row0 + r) * N_OUT + ocol] = s * dxa[m * 4 + r] * g + bi;
            }
        }
    }
}

// ---------------- fallback (fused bf16) if ws too small ----------------
__global__ __launch_bounds__(256)
void qlinear_fused(const float* __restrict__ X,
                   const int*   __restrict__ Q,
                   const float* __restrict__ S,
                   const float* __restrict__ Z,
                   const float* __restrict__ Bias,
                   float* __restrict__ O)
{
    __shared__ bf16_t As[128][32];
    __shared__ bf16_t Bs[128][32];
    const int tid = threadIdx.x, lane = tid & 63, wid = tid >> 6;
    const int wr = wid >> 1, wc = wid & 1, fr = lane & 15, fg = lane >> 4;
    const int bm = blockIdx.y * 128, bn = blockIdx.x * 128;
    const int srow = tid >> 1, scol = (tid & 1) << 4;
    const float s_n = S[bn + srow];
    const float zs_n = Z[bn + srow] * s_n;
    const float* xptr = X + (size_t)(bm + srow) * K_IN + scol;
    const int*   qptr = Q + (size_t)(bn + srow) * K_IN + scol;
    f32x4 acc[4][4] = {};
    for (int k0 = 0; k0 < K_IN; k0 += 32) {
        float a[16]; int qi[16];
        { const float4* s4 = (const float4*)(xptr + k0);
          *(float4*)(a+0)=s4[0]; *(float4*)(a+4)=s4[1]; *(float4*)(a+8)=s4[2]; *(float4*)(a+12)=s4[3]; }
        { const int4* s4 = (const int4*)(qptr + k0);
          *(int4*)(qi+0)=s4[0]; *(int4*)(qi+4)=s4[1]; *(int4*)(qi+8)=s4[2]; *(int4*)(qi+12)=s4[3]; }
        float b[16];
        #pragma unroll
        for (int j = 0; j < 16; ++j) b[j] = (float)qi[j] * s_n - zs_n;
        bf16x8 pa0, pa1, pb0, pb1;
        #pragma unroll
        for (int j = 0; j < 8; ++j) {
            pa0[j]=(bf16_t)a[j]; pa1[j]=(bf16_t)a[j+8];
            pb0[j]=(bf16_t)b[j]; pb1[j]=(bf16_t)b[j+8];
        }
        *(bf16x8*)&As[srow][scol]   = pa0; *(bf16x8*)&As[srow][scol+8] = pa1;
        *(bf16x8*)&Bs[srow][scol]   = pb0; *(bf16x8*)&Bs[srow][scol+8] = pb1;
        __syncthreads();
        bf16x8 af[4], bfv[4];
        #pragma unroll
        for (int m = 0; m < 4; ++m) af[m] = *(const bf16x8*)&As[wr*64+m*16+fr][fg*8];
        #pragma unroll
        for (int n = 0; n < 4; ++n) bfv[n] = *(const bf16x8*)&Bs[wc*64+n*16+fr][fg*8];
        #pragma unroll
        for (int m = 0; m < 4; ++m)
            #pragma unroll
            for (int n = 0; n < 4; ++n)
                acc[m][n] = __builtin_amdgcn_mfma_f32_16x16x32_bf16(af[m], bfv[n], acc[m][n], 0,0,0);
        __syncthreads();
    }
    #pragma unroll
    for (int n = 0; n < 4; ++n) {
        const int col = bn + wc*64 + n*16 + fr;
        const float bv = Bias[col];
        #pragma unroll
        for (int m = 0; m < 4; ++m) {
            const int row0 = bm + wr*64 + m*16 + fg*4;
            #pragma unroll
            for (int r = 0; r < 4; ++r)
                O[(size_t)(row0 + r) * N_OUT + col] = acc[m][n][r] + bv;
        }
    }
}

extern "C" void kernel_launch(void* const* d_in, const int* in_sizes, int n_in,
                              void* d_out, int out_size, void* d_ws, size_t ws_size,
                              hipStream_t stream) {
    const float* X    = (const float*)d_in[0];
    const int*   Q    = (const int*)d_in[1];
    const float* S    = (const float*)d_in[2];
    const float* Z    = (const float*)d_in[3];
    const float* Bias = (const float*)d_in[4];
    float* O = (float*)d_out;

    const size_t wbytes = (size_t)N_OUT * K_IN;          // 45,088,768
    const size_t xbytes = (size_t)M_TOK * K_IN;          //  8,388,608
    const size_t need   = wbytes + xbytes + 4 * M_TOK * sizeof(float) + 64;

    if (ws_size >= need) {
        signed char* W8 = (signed char*)d_ws;
        signed char* X8 = (signed char*)d_ws + wbytes;
        float* dxv = (float*)((char*)d_ws + wbytes + xbytes);
        float* sxv = dxv + M_TOK;
        pack_w<<<2048, 256, 0, stream>>>(Q, W8);
        quant_x<<<M_TOK, 256, 0, stream>>>(X, X8, dxv, sxv);
        gemm_i8<<<dim3(688), 512, 0, stream>>>(X8, W8, dxv, sxv, S, Z, Bias, O);
    } else {
        dim3 grid(N_OUT / 128, M_TOK / 128);
        qlinear_fused<<<grid, 256, 0, stream>>>(X, Q, S, Z, Bias, O);
    }
}

// Round 12
// 174.182 us; speedup vs baseline: 6.5334x; 1.2253x over previous
//
#include <hip/hip_runtime.h>
#include <hip/hip_bf16.h>
#include <stdint.h>

typedef __bf16 bf16_t;
typedef bf16_t bf16x8 __attribute__((ext_vector_type(8)));
typedef float  f32x4  __attribute__((ext_vector_type(4)));
typedef int    i32x4  __attribute__((ext_vector_type(4)));

#define M_TOK 2048
#define N_OUT 11008
#define K_IN  4096
#define N16   (N_OUT / 16)   // 688

// ---------- pre-pass 1: pack W int32 -> i8 (q-128), FRAGMENT-LINEAR ----------
// W8t layout: B-frag for (K-tile kt, col-group n16) is 1 KB at
//   ((kt*688 + n16)*64 + lane)*16, lane = fg*16 + fr, fr = col%16, fg = ksub.
// Block = 16 rows (one n16) x K. thread t: fr=t&15, fg=(t>>4)&3, w=t>>6;
// iterates kt = 4*kt2 + w. Reads: 16B x4 consecutive per thread (256B per
// fr-group); writes: wave-contiguous 1 KB (perfectly coalesced).
__global__ __launch_bounds__(256)
void pack_wt(const int* __restrict__ Q, signed char* __restrict__ W8t)
{
    const int n16 = blockIdx.x;
    const int t   = threadIdx.x;
    const int fr  = t & 15;
    const int fg  = (t >> 4) & 3;
    const int w   = t >> 6;

    const int* qrow = Q + (size_t)(n16 * 16 + fr) * K_IN + fg * 16;
    signed char* wout = W8t + ((size_t)n16 * 64 + (t & 63)) * 16;

    #pragma unroll 4
    for (int kt2 = 0; kt2 < 16; ++kt2) {
        const int kt = kt2 * 4 + w;
        const int4* q4 = (const int4*)(qrow + kt * 64);
        unsigned int pk[4];
        #pragma unroll
        for (int j = 0; j < 4; ++j) {
            const int4 q = q4[j];
            pk[j] =  (unsigned int)((q.x - 128) & 255)
                  | ((unsigned int)((q.y - 128) & 255) << 8)
                  | ((unsigned int)((q.z - 128) & 255) << 16)
                  | ((unsigned int)((q.w - 128) & 255) << 24);
        }
        *(int4*)(wout + (size_t)kt * (N16 * 1024)) = *(const int4*)pk;
    }
}

// -------- pre-pass 2: per-token symmetric i8 quant of X, FRAGMENT-LINEAR -----
// (verified r11) A-frag (kt, m16) = 1 KB at ((kt*128 + m16)*64 + lane)*16.
__global__ __launch_bounds__(256)
void quant_x(const float* __restrict__ X, signed char* __restrict__ X8,
             float* __restrict__ dxv, float* __restrict__ sxv)
{
    const int row = blockIdx.x;
    const int tid = threadIdx.x;
    const float* xr = X + (size_t)row * K_IN + tid * 16;
    float v[16];
    #pragma unroll
    for (int j = 0; j < 4; ++j)
        *(float4*)(v + j * 4) = ((const float4*)xr)[j];

    float amax = 0.f;
    #pragma unroll
    for (int j = 0; j < 16; ++j) amax = fmaxf(amax, fabsf(v[j]));
    #pragma unroll
    for (int m = 1; m < 64; m <<= 1)
        amax = fmaxf(amax, __shfl_xor(amax, m));
    __shared__ float wmax[4];
    __shared__ int   wsum[4];
    const int wv = tid >> 6;
    if ((tid & 63) == 0) wmax[wv] = amax;
    __syncthreads();
    amax = fmaxf(fmaxf(wmax[0], wmax[1]), fmaxf(wmax[2], wmax[3]));
    amax = fmaxf(amax, 1e-20f);
    const float inv = 127.f / amax;

    int sum = 0;
    unsigned int pk[4];
    #pragma unroll
    for (int j = 0; j < 4; ++j) {
        unsigned int p = 0;
        #pragma unroll
        for (int i = 0; i < 4; ++i) {
            int xi = (int)__builtin_rintf(v[j * 4 + i] * inv);
            xi = max(-127, min(127, xi));
            sum += xi;
            p |= ((unsigned int)(xi & 255)) << (8 * i);
        }
        pk[j] = p;
    }
    const size_t toff = (((size_t)(tid >> 2) * 128 + (row >> 4)) * 64
                         + (size_t)((tid & 3) * 16 + (row & 15))) * 16;
    *(int4*)(X8 + toff) = *(const int4*)pk;

    #pragma unroll
    for (int m = 1; m < 64; m <<= 1) sum += __shfl_xor(sum, m);
    if ((tid & 63) == 0) wsum[wv] = sum;
    __syncthreads();
    if (tid == 0) {
        dxv[row] = amax * (1.f / 127.f);
        sxv[row] = (float)(wsum[0] + wsum[1] + wsum[2] + wsum[3]);
    }
}

// ---------------- main GEMM: i8 128x256, NO LDS, NO BARRIERS -----------------
// 4 waves (2M x 2N), per-wave 64x128 output = 4x8 16x16 tiles (acc 128 VGPR).
// Both operands fragment-linear in global; per K-tile each wave loads
// 4 A-frags + 8 B-frags (coalesced 1KB dwordx4) prefetched one tile ahead
// into named P/Q reg sets (rule-20: static names, no runtime indexing).
// Waves free-run: vmem latency of wave A hides under wave B's MFMA (m114).

#define LOAD_AB(DA, DB, KT) do {                                               \
    const char* ap_ = gAt + (size_t)(KT) * (128 * 1024);                       \
    DA##0 = *(const i32x4*)(ap_ + 0 * 1024);                                   \
    DA##1 = *(const i32x4*)(ap_ + 1 * 1024);                                   \
    DA##2 = *(const i32x4*)(ap_ + 2 * 1024);                                   \
    DA##3 = *(const i32x4*)(ap_ + 3 * 1024);                                   \
    const char* bp_ = gBt + (size_t)(KT) * (N16 * 1024);                       \
    DB##0 = *(const i32x4*)(bp_ + 0 * 1024);                                   \
    DB##1 = *(const i32x4*)(bp_ + 1 * 1024);                                   \
    DB##2 = *(const i32x4*)(bp_ + 2 * 1024);                                   \
    DB##3 = *(const i32x4*)(bp_ + 3 * 1024);                                   \
    DB##4 = *(const i32x4*)(bp_ + 4 * 1024);                                   \
    DB##5 = *(const i32x4*)(bp_ + 5 * 1024);                                   \
    DB##6 = *(const i32x4*)(bp_ + 6 * 1024);                                   \
    DB##7 = *(const i32x4*)(bp_ + 7 * 1024);                                   \
} while (0)

#define MMQ(FA, FB, MQ, NQ)                                                    \
    acc[MQ][NQ] = __builtin_amdgcn_mfma_i32_16x16x64_i8(FA##MQ, FB##NQ, acc[MQ][NQ], 0, 0, 0)

#define MFMA32(FA, FB) do {                                                    \
    __builtin_amdgcn_s_setprio(1);                                             \
    MMQ(FA, FB, 0, 0); MMQ(FA, FB, 0, 1); MMQ(FA, FB, 0, 2); MMQ(FA, FB, 0, 3);\
    MMQ(FA, FB, 0, 4); MMQ(FA, FB, 0, 5); MMQ(FA, FB, 0, 6); MMQ(FA, FB, 0, 7);\
    MMQ(FA, FB, 1, 0); MMQ(FA, FB, 1, 1); MMQ(FA, FB, 1, 2); MMQ(FA, FB, 1, 3);\
    MMQ(FA, FB, 1, 4); MMQ(FA, FB, 1, 5); MMQ(FA, FB, 1, 6); MMQ(FA, FB, 1, 7);\
    MMQ(FA, FB, 2, 0); MMQ(FA, FB, 2, 1); MMQ(FA, FB, 2, 2); MMQ(FA, FB, 2, 3);\
    MMQ(FA, FB, 2, 4); MMQ(FA, FB, 2, 5); MMQ(FA, FB, 2, 6); MMQ(FA, FB, 2, 7);\
    MMQ(FA, FB, 3, 0); MMQ(FA, FB, 3, 1); MMQ(FA, FB, 3, 2); MMQ(FA, FB, 3, 3);\
    MMQ(FA, FB, 3, 4); MMQ(FA, FB, 3, 5); MMQ(FA, FB, 3, 6); MMQ(FA, FB, 3, 7);\
    __builtin_amdgcn_s_setprio(0);                                             \
} while (0)

// region: prefetch (NA,NB) <- tile KTN, then MFMA on (CA,CB)
#define REGION12(CA, CB, NA, NB, KTN) do {                                     \
    LOAD_AB(NA, NB, KTN);                                                      \
    MFMA32(CA, CB);                                                            \
} while (0)

__global__ __launch_bounds__(256, 2)
void gemm_i8(const signed char* __restrict__ A8t,  // X8 fragment-linear (8 MB)
             const signed char* __restrict__ B8t,  // W8 fragment-linear (45 MB)
             const float* __restrict__ dxv,        // [M_TOK]
             const float* __restrict__ sxv,        // [M_TOK]
             const float* __restrict__ S,
             const float* __restrict__ Z,
             const float* __restrict__ Bias,
             float* __restrict__ O)
{
    const int tid  = threadIdx.x;
    const int lane = tid & 63;
    const int wid  = tid >> 6;
    const int wr   = wid >> 1;   // 0..1  (M half, 64 rows)
    const int wc   = wid & 1;    // 0..1  (N half, 128 cols)
    const int fr   = lane & 15;
    const int fg   = lane >> 4;

    // XCD partition (r10-verified): xcd owns cols 5x..5x+4 x 16 by + spill.
    const int bid = blockIdx.x;
    const int xcd = bid & 7;
    const int k   = bid >> 3;           // 0..85
    int col, by;
    if (k < 80) { col = 5 * xcd + (k >> 4); by = k & 15; }
    else        { const int e = k - 80; col = 40 + (e >> 1); by = 2 * xcd + (e & 1); }
    const long bm = (long)by * 128;
    const long bn = (long)col * 256;

    // fragment-linear bases (lane folded in)
    const char* gAt = (const char*)A8t
                    + (((size_t)(by * 8 + wr * 4)) * 64 + lane) * 16;
    const char* gBt = (const char*)B8t
                    + (((size_t)(col * 16 + wc * 8)) * 64 + lane) * 16;

    i32x4 acc[4][8] = {};
    i32x4 pa0, pa1, pa2, pa3, pb0, pb1, pb2, pb3, pb4, pb5, pb6, pb7;
    i32x4 qa0, qa1, qa2, qa3, qb0, qb1, qb2, qb3, qb4, qb5, qb6, qb7;

    // prologue: load tile 0 into P
    LOAD_AB(pa, pb, 0);

    #pragma unroll 1
    for (int i = 0; i < 31; ++i) {
        REGION12(pa, pb, qa, qb, 2 * i + 1);   // t = 2i   : MFMA P, prefetch Q
        REGION12(qa, qb, pa, pb, 2 * i + 2);   // t = 2i+1 : MFMA Q, prefetch P
    }
    REGION12(pa, pb, qa, qb, 63);              // t = 62
    MFMA32(qa, qb);                            // t = 63

    // epilogue: y = s*dx*(acc + (128-zp)*sx) + bias
    // C/D: col = lane&15, row = (lane>>4)*4 + reg (shape-determined, verified)
    float dxa[16], sxa[16];
    #pragma unroll
    for (int m = 0; m < 4; ++m)
        #pragma unroll
        for (int r = 0; r < 4; ++r) {
            const int row = (int)bm + wr * 64 + m * 16 + (fg << 2) + r;
            dxa[m * 4 + r] = dxv[row];
            sxa[m * 4 + r] = sxv[row];
        }
    #pragma unroll
    for (int n = 0; n < 8; ++n) {
        const long ocol = bn + wc * 128 + n * 16 + fr;
        const float s  = S[ocol];
        const float f  = 128.f - Z[ocol];
        const float bi = Bias[ocol];
        #pragma unroll
        for (int m = 0; m < 4; ++m) {
            const long row0 = bm + wr * 64 + m * 16 + (fg << 2);
            #pragma unroll
            for (int r = 0; r < 4; ++r) {
                const float g = (float)acc[m][n][r] + f * sxa[m * 4 + r];
                O[(size_t)(row0 + r) * N_OUT + ocol] = s * dxa[m * 4 + r] * g + bi;
            }
        }
    }
}

// ---------------- fallback (fused bf16) if ws too small ----------------
__global__ __launch_bounds__(256)
void qlinear_fused(const float* __restrict__ X,
                   const int*   __restrict__ Q,
                   const float* __restrict__ S,
                   const float* __restrict__ Z,
                   const float* __restrict__ Bias,
                   float* __restrict__ O)
{
    __shared__ bf16_t As[128][32];
    __shared__ bf16_t Bs[128][32];
    const int tid = threadIdx.x, lane = tid & 63, wid = tid >> 6;
    const int wr = wid >> 1, wc = wid & 1, fr = lane & 15, fg = lane >> 4;
    const int bm = blockIdx.y * 128, bn = blockIdx.x * 128;
    const int srow = tid >> 1, scol = (tid & 1) << 4;
    const float s_n = S[bn + srow];
    const float zs_n = Z[bn + srow] * s_n;
    const float* xptr = X + (size_t)(bm + srow) * K_IN + scol;
    const int*   qptr = Q + (size_t)(bn + srow) * K_IN + scol;
    f32x4 acc[4][4] = {};
    for (int k0 = 0; k0 < K_IN; k0 += 32) {
        float a[16]; int qi[16];
        { const float4* s4 = (const float4*)(xptr + k0);
          *(float4*)(a+0)=s4[0]; *(float4*)(a+4)=s4[1]; *(float4*)(a+8)=s4[2]; *(float4*)(a+12)=s4[3]; }
        { const int4* s4 = (const int4*)(qptr + k0);
          *(int4*)(qi+0)=s4[0]; *(int4*)(qi+4)=s4[1]; *(int4*)(qi+8)=s4[2]; *(int4*)(qi+12)=s4[3]; }
        float b[16];
        #pragma unroll
        for (int j = 0; j < 16; ++j) b[j] = (float)qi[j] * s_n - zs_n;
        bf16x8 pa0, pa1, pb0, pb1;
        #pragma unroll
        for (int j = 0; j < 8; ++j) {
            pa0[j]=(bf16_t)a[j]; pa1[j]=(bf16_t)a[j+8];
            pb0[j]=(bf16_t)b[j]; pb1[j]=(bf16_t)b[j+8];
        }
        *(bf16x8*)&As[srow][scol]   = pa0; *(bf16x8*)&As[srow][scol+8] = pa1;
        *(bf16x8*)&Bs[srow][scol]   = pb0; *(bf16x8*)&Bs[srow][scol+8] = pb1;
        __syncthreads();
        bf16x8 af[4], bfv[4];
        #pragma unroll
        for (int m = 0; m < 4; ++m) af[m] = *(const bf16x8*)&As[wr*64+m*16+fr][fg*8];
        #pragma unroll
        for (int n = 0; n < 4; ++n) bfv[n] = *(const bf16x8*)&Bs[wc*64+n*16+fr][fg*8];
        #pragma unroll
        for (int m = 0; m < 4; ++m)
            #pragma unroll
            for (int n = 0; n < 4; ++n)
                acc[m][n] = __builtin_amdgcn_mfma_f32_16x16x32_bf16(af[m], bfv[n], acc[m][n], 0,0,0);
        __syncthreads();
    }
    #pragma unroll
    for (int n = 0; n < 4; ++n) {
        const int col = bn + wc*64 + n*16 + fr;
        const float bv = Bias[col];
        #pragma unroll
        for (int m = 0; m < 4; ++m) {
            const int row0 = bm + wr*64 + m*16 + fg*4;
            #pragma unroll
            for (int r = 0; r < 4; ++r)
                O[(size_t)(row0 + r) * N_OUT + col] = acc[m][n][r] + bv;
        }
    }
}

extern "C" void kernel_launch(void* const* d_in, const int* in_sizes, int n_in,
                              void* d_out, int out_size, void* d_ws, size_t ws_size,
                              hipStream_t stream) {
    const float* X    = (const float*)d_in[0];
    const int*   Q    = (const int*)d_in[1];
    const float* S    = (const float*)d_in[2];
    const float* Z    = (const float*)d_in[3];
    const float* Bias = (const float*)d_in[4];
    float* O = (float*)d_out;

    const size_t wbytes = (size_t)N_OUT * K_IN;          // 45,088,768
    const size_t xbytes = (size_t)M_TOK * K_IN;          //  8,388,608
    const size_t need   = wbytes + xbytes + 4 * M_TOK * sizeof(float) + 64;

    if (ws_size >= need) {
        signed char* W8t = (signed char*)d_ws;
        signed char* X8t = (signed char*)d_ws + wbytes;
        float* dxv = (float*)((char*)d_ws + wbytes + xbytes);
        float* sxv = dxv + M_TOK;
        pack_wt<<<N16, 256, 0, stream>>>(Q, W8t);
        quant_x<<<M_TOK, 256, 0, stream>>>(X, X8t, dxv, sxv);
        gemm_i8<<<dim3(688), 256, 0, stream>>>(X8t, W8t, dxv, sxv, S, Z, Bias, O);
    } else {
        dim3 grid(N_OUT / 128, M_TOK / 128);
        qlinear_fused<<<grid, 256, 0, stream>>>(X, Q, S, Z, Bias, O);
    }
}